// Round 9
// baseline (106.288 us; speedup 1.0000x reference)
//
#include <hip/hip_runtime.h>
#include <math.h>

// Problem constants (from reference):
//   vol: (B=1, C=1, W=96, H=96, D=64) float32, row-major -> vol[(x*96+y)*64+z]
//   out: (B,C,U=96,A=90,V=64) float32 -> out[(u*90+a)*64+v]
namespace {
constexpr int NA = 90, NU = 96, NV = 64, NW = 96, NH = 96, ND = 64;
constexpr int NRAY   = NA * NU;      // 8640
constexpr int NSTEPS = NH + NW + 2;  // 194
constexpr int NPAD   = 208;          // entries padded to x16 batches
constexpr int ROW    = 209;          // LDS row stride (odd -> conflict-free)
constexpr int TILE   = 8;            // rays per block = waves per block
constexpr int NBLK   = NRAY / TILE;  // 1080 blocks (~4.2/CU)
}

// R9: straight-line trace. R8's doubled-gather attribution: gather = 3.7us,
// trace = ~42us of R7's 47.4 (≈520 cyc/step for one wave/SIMD). The culprit
// is per-step control: __ballot -> scalar VCC read -> s_cbranch, plus
// if(valid) exec save/restore, fully exposed with no co-resident waves.
// Fix: fixed 194-iteration loop, ALL predication via cndmask, unconditional
// packed ds_write_b64 per step (invalid steps write zeros = exactly the pad,
// valid is a sticky prefix). One exec-mask set for the whole loop.
__global__ __launch_bounds__(512)
void siddon_fused(const float* __restrict__ vol, float* __restrict__ out)
{
    __shared__ int2 sEnt[TILE * ROW];  // .x = BYTE offset of vol row, .y = weight bits
    __shared__ int  sCnt[TILE];        // valid count padded to multiple of 16

    const int tid  = threadIdx.x;
    const int tile = blockIdx.x;

    // ---------------- Phase 1: trace (wave 0, lanes 0..TILE-1) ----------------
    if (tid < 64) {
        const int  rl     = tid;
        const bool tracer = rl < TILE;
        const int  ray    = tile * TILE + (tracer ? rl : 0);
        const int  a = ray / NU;
        const int  u = ray - a * NU;

        const float EPSf = 1e-12f;
        const float INF  = __builtin_inff();
        const float DIAG = 1.41421356237309514547f;

        const float ang = (float)a * (float)(3.14159265358979323846 / 90.0);
        const float dx = (float)cos((double)ang);
        const float dy = (float)sin((double)ang);
        const float uu = (float)u - 47.5f;
        const float x0 = __fmul_rn(-uu, dy);
        const float y0 = __fmul_rn( uu, dx);

        const float xmin = -47.5f, xmax = 47.5f;
        const float ymin = -47.5f, ymax = 47.5f;

        float tx0, tx1;
        {
            const bool par = fabsf(dx) < EPSf;
            const float safe = par ? 1.0f : dx;
            const float t0 = __fdiv_rn(xmin - x0, safe);
            const float t1 = __fdiv_rn(xmax - x0, safe);
            const float lo = fminf(t0, t1), hi = fmaxf(t0, t1);
            const bool inside = (x0 >= xmin) && (x0 <= xmax);
            tx0 = par ? (inside ? -INF : INF) : lo;
            tx1 = par ? (inside ?  INF : -INF) : hi;
        }
        float ty0, ty1;
        {
            const bool par = fabsf(dy) < EPSf;
            const float safe = par ? 1.0f : dy;
            const float t0 = __fdiv_rn(ymin - y0, safe);
            const float t1 = __fdiv_rn(ymax - y0, safe);
            const float lo = fminf(t0, t1), hi = fmaxf(t0, t1);
            const bool inside = (y0 >= ymin) && (y0 <= ymax);
            ty0 = par ? (inside ? -INF : INF) : lo;
            ty1 = par ? (inside ?  INF : -INF) : hi;
        }

        const float t_entry = fmaxf(tx0, ty0);
        const float t_exit  = fminf(tx1, ty1);
        bool  alive = tracer && (t_entry < t_exit);
        const float te  = (t_entry < t_exit) ? t_entry : 0.0f;
        const float tex = (t_entry < t_exit) ? t_exit  : 0.0f;

        float x = __fadd_rn(x0, __fmul_rn(te, dx));
        float y = __fadd_rn(y0, __fmul_rn(te, dy));
        int i = (int)fminf(fmaxf(rintf(__fadd_rn(x, 47.5f)), 0.0f), 95.0f);
        int j = (int)fminf(fmaxf(rintf(__fadd_rn(y, 47.5f)), 0.0f), 95.0f);
        float t = te;

        const bool okx = fabsf(dx) > EPSf;
        const bool oky = fabsf(dy) > EPSf;
        // reciprocal-mul instead of per-step IEEE div: <=2 ulp vs reference
        // (validated R2-R8: absmax stayed 0.25 vs 1.18 threshold).
        const float inv_dx = okx ? __fdiv_rn(1.0f, dx) : 0.0f;
        const float inv_dy = oky ? __fdiv_rn(1.0f, dy) : 0.0f;
        const float wscale = __fdiv_rn(DIAG, fmaxf(fabsf(dx) + fabsf(dy), EPSf));
        const float tex_m_eps = __fadd_rn(tex, -EPSf);
        // next-boundary coords, tracked incrementally (+-1.0 exact: |.|<150<2^23)
        const float cx = (dx > 0.0f) ? -47.0f : -48.0f;
        const float cy = (dy > 0.0f) ? -47.0f : -48.0f;
        float xn = (float)i + cx;      // == (i +- 0.5) - 47.5 exactly
        float yn = (float)j + cy;
        const float sxf = (dx > 0.0f) ? 1.0f : -1.0f;
        const float syf = (dy > 0.0f) ? 1.0f : -1.0f;
        const int   si  = (dx > 0.0f) ? 1 : -1;   // dx==0 -> never selected
        const int   sj  = (dy > 0.0f) ? 1 : -1;   // dy==0 -> never selected

        if (tracer) {                  // exec mask set ONCE for the whole loop
            int2* __restrict__ myRow = &sEnt[rl * ROW];
            int n = 0;
            for (int step = 0; step < NSTEPS; ++step) {
                const bool valid = alive && (t < tex_m_eps);
                const float txc = okx ? __fmul_rn(xn - x, inv_dx) : INF;
                const float tyc = oky ? __fmul_rn(yn - y, inv_dy) : INF;
                const float dt  = fminf(fminf(txc, tyc), __fadd_rn(tex, -t));
                const float seg = fmaxf(0.0f, __fmul_rn(dt, wscale));

                int2 e;
                e.x = valid ? ((i * NH + j) << 8) : 0;   // BYTE offset into vol
                e.y = valid ? __float_as_int(seg) : 0;
                myRow[step] = e;                          // unconditional b64 store
                n += valid ? 1 : 0;

                const bool cndx = (txc <= tyc);
                const bool cndy = (tyc <= txc);
                const int i_n = i + (cndx ? si : 0);
                const int j_n = j + (cndy ? sj : 0);
                const bool inb = ((unsigned)i_n < (unsigned)NW) &&
                                 ((unsigned)j_n < (unsigned)NH);
                i  = valid ? i_n : i;
                j  = valid ? j_n : j;
                xn = valid ? (xn + (cndx ? sxf : 0.0f)) : xn;
                yn = valid ? (yn + (cndy ? syf : 0.0f)) : yn;
                x  = valid ? __fadd_rn(x, __fmul_rn(dx, dt)) : x;
                y  = valid ? __fadd_rn(y, __fmul_rn(dy, dt)) : y;
                t  = valid ? __fadd_rn(t, dt) : t;
                alive = valid && inb;
            }
            sCnt[rl] = (n + 15) & ~15;             // <= 208
            for (int p = NSTEPS; p < NPAD; ++p) {  // zero [194,208)
                int2 z; z.x = 0; z.y = 0;
                myRow[p] = z;
            }
        }
    }
    __syncthreads();

    // ---------------- Phase 2: gather (wave w -> ray w), R7 structure ----------
    // Lane L: row-in-quad r=L>>4, 16B chunk sub=L&15. One global_load_dwordx4
    // per 4 entries fetches four 256B vol rows.
    const int wid  = tid >> 6;
    const int lane = tid & 63;
    const int r    = lane >> 4;
    const int sub  = lane & 15;
    const int subOff = sub << 4;

    const int cnt = sCnt[wid];
    const int2* __restrict__ eRow = &sEnt[wid * ROW + r];  // entry n+r at [n]
    const char* __restrict__ vb   = (const char*)vol;

    float4 aA = {0,0,0,0}, aB = {0,0,0,0}, aC = {0,0,0,0}, aD = {0,0,0,0};
    for (int n = 0; n < cnt; n += 16) {
        const int2 e0 = eRow[n];        // 4-address LDS broadcast (conflict-free)
        const int2 e1 = eRow[n + 4];
        const int2 e2 = eRow[n + 8];
        const int2 e3 = eRow[n + 12];
        const float w0 = __int_as_float(e0.y);
        const float w1 = __int_as_float(e1.y);
        const float w2 = __int_as_float(e2.y);
        const float w3 = __int_as_float(e3.y);
        const float4 v0 = *(const float4*)(vb + (e0.x + subOff));  // 4 rows/instr
        const float4 v1 = *(const float4*)(vb + (e1.x + subOff));
        const float4 v2 = *(const float4*)(vb + (e2.x + subOff));
        const float4 v3 = *(const float4*)(vb + (e3.x + subOff));
        aA.x = fmaf(w0, v0.x, aA.x); aA.y = fmaf(w0, v0.y, aA.y);
        aA.z = fmaf(w0, v0.z, aA.z); aA.w = fmaf(w0, v0.w, aA.w);
        aB.x = fmaf(w1, v1.x, aB.x); aB.y = fmaf(w1, v1.y, aB.y);
        aB.z = fmaf(w1, v1.z, aB.z); aB.w = fmaf(w1, v1.w, aB.w);
        aC.x = fmaf(w2, v2.x, aC.x); aC.y = fmaf(w2, v2.y, aC.y);
        aC.z = fmaf(w2, v2.z, aC.z); aC.w = fmaf(w2, v2.w, aC.w);
        aD.x = fmaf(w3, v3.x, aD.x); aD.y = fmaf(w3, v3.y, aD.y);
        aD.z = fmaf(w3, v3.z, aD.z); aD.w = fmaf(w3, v3.w, aD.w);
    }
    float sx = (aA.x + aB.x) + (aC.x + aD.x);
    float sy = (aA.y + aB.y) + (aC.y + aD.y);
    float sz = (aA.z + aB.z) + (aC.z + aD.z);
    float sw = (aA.w + aB.w) + (aC.w + aD.w);

    // reduce across the 4 row groups: lanes {sub, 16+sub, 32+sub, 48+sub}
    sx += __shfl_xor(sx, 16, 64);  sy += __shfl_xor(sy, 16, 64);
    sz += __shfl_xor(sz, 16, 64);  sw += __shfl_xor(sw, 16, 64);
    sx += __shfl_xor(sx, 32, 64);  sy += __shfl_xor(sy, 32, 64);
    sz += __shfl_xor(sz, 32, 64);  sw += __shfl_xor(sw, 32, 64);

    if (lane < 16) {
        const int ray = tile * TILE + wid;
        const int a = ray / NU;
        const int u = ray - a * NU;
        float4 res; res.x = sx; res.y = sy; res.z = sz; res.w = sw;
        *(float4*)(out + (u * NA + a) * NV + (sub << 2)) = res;  // 256B coalesced
    }
}

extern "C" void kernel_launch(void* const* d_in, const int* in_sizes, int n_in,
                              void* d_out, int out_size, void* d_ws, size_t ws_size,
                              hipStream_t stream) {
    const float* vol = (const float*)d_in[0];
    float* out = (float*)d_out;
    hipLaunchKernelGGL(siddon_fused, dim3(NBLK), dim3(512), 0, stream, vol, out);
}

// Round 10
// 70.410 us; speedup vs baseline: 1.5096x; 1.5096x over previous
//
#include <hip/hip_runtime.h>
#include <math.h>

// Problem constants (from reference):
//   vol: (B=1, C=1, W=96, H=96, D=64) float32, row-major -> vol[(x*96+y)*64+z]
//   out: (B,C,U=96,A=90,V=64) float32 -> out[(u*90+a)*64+v]
namespace {
constexpr int NA = 90, NU = 96, NV = 64, NW = 96, NH = 96, ND = 64;
constexpr int NRAY  = NA * NU;       // 8640
constexpr int NENT  = 256;           // entries per ray (4 rounds x 64 lanes)
constexpr int CNTMAX = 208;          // gather cap (valid count <= ~195 structurally)
constexpr int TILE  = 8;             // rays per block = waves per block
constexpr int NBLK  = NRAY / TILE;   // 1080 blocks (~4.2/CU)
}

// R10: closed-form lane-parallel trace. R2-R9 lesson: a single tracer wave
// running the 194-step Siddon recurrence costs ~280 cyc/step (~23us) no
// matter how the per-step code is written -- it's a serial dependent chain
// on one wave. Fix: the traversal is a merge of two arithmetic progressions
// (x-crossing times, y-crossing times). Entry n is computed INDEPENDENTLY:
//   rank k(n) = #x-crossings among first n events  (closed-form + <=4 fixups)
//   T_n  = min(Tx_k, Ty_{n-k})          (event ending segment n)
//   prev = max(te, Tx_{k-1}, Ty_{n-k-1}) (event starting segment n)
//   dt   = min(T_n,tex) - min(prev,tex);  cell = (i0+si*k, j0+sj*(n-k))
// 64 lanes compute 64 entries -> 4 rounds replace 194 serial steps.
// Corner ties become an extra zero-weight entry (numerically free).
// Gather: R7/R9 validated quad-row structure (1 dwordx4 = four 256B vol rows).
__global__ __launch_bounds__(512)
void siddon_fused(const float* __restrict__ vol, float* __restrict__ out)
{
    __shared__ int2 sEnt[TILE][NENT];  // .x = BYTE offset of vol row, .y = weight bits
    __shared__ int  sCnt[TILE];        // valid count padded to multiple of 16

    const int tid  = threadIdx.x;
    const int wid  = tid >> 6;         // wave = ray-in-tile (ALL 8 waves trace)
    const int lane = tid & 63;
    const int tile = blockIdx.x;
    const int ray  = tile * TILE + wid;
    const int a    = ray / NU;
    const int u    = ray - a * NU;

    const float EPSf = 1e-12f;
    const float INFp = __builtin_inff();
    const float DIAG = 1.41421356237309514547f;

    // ---------------- per-ray setup (wave-uniform) ----------------
    const float ang = (float)a * (float)(3.14159265358979323846 / 90.0);
    const float dx = (float)cos((double)ang);
    const float dy = (float)sin((double)ang);
    const float uu = (float)u - 47.5f;
    const float x0 = __fmul_rn(-uu, dy);
    const float y0 = __fmul_rn( uu, dx);

    const float xmin = -47.5f, xmax = 47.5f;
    const float ymin = -47.5f, ymax = 47.5f;

    float tx0, tx1;
    {
        const bool par = fabsf(dx) < EPSf;
        const float safe = par ? 1.0f : dx;
        const float t0 = __fdiv_rn(xmin - x0, safe);
        const float t1 = __fdiv_rn(xmax - x0, safe);
        const float lo = fminf(t0, t1), hi = fmaxf(t0, t1);
        const bool inside = (x0 >= xmin) && (x0 <= xmax);
        tx0 = par ? (inside ? -INFp : INFp) : lo;
        tx1 = par ? (inside ?  INFp : -INFp) : hi;
    }
    float ty0, ty1;
    {
        const bool par = fabsf(dy) < EPSf;
        const float safe = par ? 1.0f : dy;
        const float t0 = __fdiv_rn(ymin - y0, safe);
        const float t1 = __fdiv_rn(ymax - y0, safe);
        const float lo = fminf(t0, t1), hi = fmaxf(t0, t1);
        const bool inside = (y0 >= ymin) && (y0 <= ymax);
        ty0 = par ? (inside ? -INFp : INFp) : lo;
        ty1 = par ? (inside ?  INFp : -INFp) : hi;
    }

    const float t_entry = fmaxf(tx0, ty0);
    const float t_exit  = fminf(tx1, ty1);
    const bool  alive0  = t_entry < t_exit;
    const float te  = alive0 ? t_entry : 0.0f;
    const float tex = alive0 ? t_exit  : 0.0f;

    const float xe = __fadd_rn(x0, __fmul_rn(te, dx));
    const float ye = __fadd_rn(y0, __fmul_rn(te, dy));
    const int i0 = (int)fminf(fmaxf(rintf(__fadd_rn(xe, 47.5f)), 0.0f), 95.0f);
    const int j0 = (int)fminf(fmaxf(rintf(__fadd_rn(ye, 47.5f)), 0.0f), 95.0f);

    const bool okx = fabsf(dx) > EPSf;
    const bool oky = fabsf(dy) > EPSf;
    const float inv_dx = okx ? __fdiv_rn(1.0f, dx) : 0.0f;
    const float inv_dy = oky ? __fdiv_rn(1.0f, dy) : 0.0f;
    const float wscale = __fdiv_rn(DIAG, fmaxf(fabsf(dx) + fabsf(dy), EPSf));
    const float tex_m_eps = __fadd_rn(tex, -EPSf);

    // AP of x-crossing times: Ax + k*px (px = 1/|dx|), absolute t.
    // First boundary from start cell: (i0 + cx) where cx = +-0.5 - 47.5.
    const float cx = (dx > 0.0f) ? -47.0f : -48.0f;
    const float cy = (dy > 0.0f) ? -47.0f : -48.0f;
    const float Ax = okx ? __fadd_rn(te, __fmul_rn(((float)i0 + cx) - xe, inv_dx)) : INFp;
    const float Ay = oky ? __fadd_rn(te, __fmul_rn(((float)j0 + cy) - ye, inv_dy)) : INFp;
    const float px = okx ? fabsf(inv_dx) : 0.0f;   // si*inv_dx == |inv_dx|
    const float py = oky ? fabsf(inv_dy) : 0.0f;
    const int   si = (dx > 0.0f) ? 1 : -1;
    const int   sj = (dy > 0.0f) ? 1 : -1;

    // rank estimate constants: k ~= (Ay - Ax + n*py) / (px + py)
    // (!oky: Cc=+INF -> k=n; !okx: Cc=-INF -> k=0; clamped in float, pre-cast)
    const float inv_pq = __fdiv_rn(1.0f, px + py);
    const float Cc = Ay - Ax;

    // ---------------- lane-parallel trace: 4 rounds of 64 entries ----------------
    int2* __restrict__ myRow = &sEnt[wid][0];
    int cnt = 0;
    #pragma unroll
    for (int rnd = 0; rnd < 4; ++rnd) {
        const int n = (rnd << 6) + lane;
        const float nf = (float)n;

        float kf = __fmul_rn(__fmaf_rn(nf, py, Cc), inv_pq);
        kf = fminf(fmaxf(kf, 0.0f), nf);       // also collapses +-INF safely
        int k = (int)rintf(kf);

        // partition fixup: valid iff Tx_{k-1} <= Ty_{n-k} and Ty_{n-k-1} <= Tx_k.
        // -INF masking makes the k>0 / k<n guards implicit. Ties: either order
        // is fine (the disputed segment has dt==0 -> weight 0).
        #pragma unroll
        for (int it = 0; it < 4; ++it) {
            const int m = n - k;
            const float Txk   = __fmaf_rn((float)k, px, Ax);
            const float Txkm1 = (k > 0) ? __fmaf_rn((float)(k - 1), px, Ax) : -INFp;
            const float Tyl   = __fmaf_rn((float)m, py, Ay);
            const float Tylm1 = (m > 0) ? __fmaf_rn((float)(m - 1), py, Ay) : -INFp;
            const bool dec = (Txkm1 > Tyl);
            const bool inc = (!dec) && (Tylm1 > Txk);
            k += inc ? 1 : (dec ? -1 : 0);
        }

        const int m = n - k;
        const float Txk   = __fmaf_rn((float)k, px, Ax);
        const float Txkm1 = (k > 0) ? __fmaf_rn((float)(k - 1), px, Ax) : -INFp;
        const float Tyl   = __fmaf_rn((float)m, py, Ay);
        const float Tylm1 = (m > 0) ? __fmaf_rn((float)(m - 1), py, Ay) : -INFp;

        const float Tn   = fminf(Txk, Tyl);                 // event ending segment n
        const float prev = fmaxf(te, fmaxf(Txkm1, Tylm1));  // event starting it
        const float dt   = __fadd_rn(fminf(Tn, tex), -fminf(prev, tex));
        const bool active = alive0 && (prev < tex_m_eps);
        float w = __fmul_rn(fmaxf(0.0f, dt), wscale);
        w = active ? w : 0.0f;

        const int ii = min(95, max(0, i0 + ((si > 0) ? k : -k)));
        const int jj = min(95, max(0, j0 + ((sj > 0) ? m : -m)));
        int2 e;
        e.x = (ii * NH + jj) << 8;             // BYTE offset into vol
        e.y = __float_as_int(w);
        myRow[n] = e;                          // 512B contiguous per round

        cnt += (int)__popcll(__ballot(active));
    }
    if (lane == 0) sCnt[wid] = min((cnt + 15) & ~15, CNTMAX);
    __syncthreads();

    // ---------------- gather (wave w -> ray w), R7/R9 validated structure ------
    // Lane L: row-in-quad r=L>>4, 16B chunk sub=L&15. One global_load_dwordx4
    // per 4 entries fetches four 256B vol rows.
    const int r   = lane >> 4;
    const int sub = lane & 15;
    const int subOff = sub << 4;

    const int cap = sCnt[wid];
    const int2* __restrict__ eRow = &sEnt[wid][r];   // entry n+r at [n]
    const char* __restrict__ vb   = (const char*)vol;

    float4 aA = {0,0,0,0}, aB = {0,0,0,0}, aC = {0,0,0,0}, aD = {0,0,0,0};
    for (int n = 0; n < cap; n += 16) {
        const int2 e0 = eRow[n];        // 4-address LDS broadcast (conflict-free)
        const int2 e1 = eRow[n + 4];
        const int2 e2 = eRow[n + 8];
        const int2 e3 = eRow[n + 12];
        const float w0 = __int_as_float(e0.y);
        const float w1 = __int_as_float(e1.y);
        const float w2 = __int_as_float(e2.y);
        const float w3 = __int_as_float(e3.y);
        const float4 v0 = *(const float4*)(vb + (e0.x + subOff));  // 4 rows/instr
        const float4 v1 = *(const float4*)(vb + (e1.x + subOff));
        const float4 v2 = *(const float4*)(vb + (e2.x + subOff));
        const float4 v3 = *(const float4*)(vb + (e3.x + subOff));
        aA.x = fmaf(w0, v0.x, aA.x); aA.y = fmaf(w0, v0.y, aA.y);
        aA.z = fmaf(w0, v0.z, aA.z); aA.w = fmaf(w0, v0.w, aA.w);
        aB.x = fmaf(w1, v1.x, aB.x); aB.y = fmaf(w1, v1.y, aB.y);
        aB.z = fmaf(w1, v1.z, aB.z); aB.w = fmaf(w1, v1.w, aB.w);
        aC.x = fmaf(w2, v2.x, aC.x); aC.y = fmaf(w2, v2.y, aC.y);
        aC.z = fmaf(w2, v2.z, aC.z); aC.w = fmaf(w2, v2.w, aC.w);
        aD.x = fmaf(w3, v3.x, aD.x); aD.y = fmaf(w3, v3.y, aD.y);
        aD.z = fmaf(w3, v3.z, aD.z); aD.w = fmaf(w3, v3.w, aD.w);
    }
    float sx = (aA.x + aB.x) + (aC.x + aD.x);
    float sy = (aA.y + aB.y) + (aC.y + aD.y);
    float sz = (aA.z + aB.z) + (aC.z + aD.z);
    float sw = (aA.w + aB.w) + (aC.w + aD.w);

    // reduce across the 4 row groups: lanes {sub, 16+sub, 32+sub, 48+sub}
    sx += __shfl_xor(sx, 16, 64);  sy += __shfl_xor(sy, 16, 64);
    sz += __shfl_xor(sz, 16, 64);  sw += __shfl_xor(sw, 16, 64);
    sx += __shfl_xor(sx, 32, 64);  sy += __shfl_xor(sy, 32, 64);
    sz += __shfl_xor(sz, 32, 64);  sw += __shfl_xor(sw, 32, 64);

    if (lane < 16) {
        float4 res; res.x = sx; res.y = sy; res.z = sz; res.w = sw;
        *(float4*)(out + (u * NA + a) * NV + (sub << 2)) = res;  // 256B coalesced
    }
}

extern "C" void kernel_launch(void* const* d_in, const int* in_sizes, int n_in,
                              void* d_out, int out_size, void* d_ws, size_t ws_size,
                              hipStream_t stream) {
    const float* vol = (const float*)d_in[0];
    float* out = (float*)d_out;
    hipLaunchKernelGGL(siddon_fused, dim3(NBLK), dim3(512), 0, stream, vol, out);
}